// Round 2
// baseline (766.552 us; speedup 1.0000x reference)
//
#include <hip/hip_runtime.h>
#include <hip/hip_bf16.h>

#define S_IMG 16384
#define N_TXT 4096
#define DIM   512
#define KDIM  512

typedef __attribute__((ext_vector_type(8))) short bf16x8;
typedef __attribute__((ext_vector_type(4))) float f32x4;

__device__ __forceinline__ short f2bf(float f) {
  unsigned u = __float_as_uint(f);
  u += 0x7FFFu + ((u >> 16) & 1u);   // RNE
  return (short)(u >> 16);
}

__device__ __forceinline__ float softplus_f(float x) {
  return fmaxf(x, 0.0f) + log1pf(expf(-fabsf(x)));
}

// ---------------- init: sentinel for segment-min, zero the loss accumulator ----
__global__ __launch_bounds__(256) void init_kernel(
    unsigned long long* __restrict__ packed, float* __restrict__ out_loss) {
  const int i = blockIdx.x * 256 + threadIdx.x;
  packed[i] = 0xFFFFFFFFFFFFFFFFull;
  if (i == 0) out_loss[0] = 0.0f;
}

// ---------------- L2 normalize rows (txt), emit f32 (output) + bf16 (MFMA) ----
__global__ __launch_bounds__(256) void normalize_kernel(
    const float* __restrict__ in, float* __restrict__ outf,
    short* __restrict__ outb) {
  const int w = threadIdx.x >> 6, l = threadIdx.x & 63;
  const size_t row = (size_t)blockIdx.x * 4 + w;
  const float4* r4 = (const float4*)(in + row * DIM);
  float4 a = r4[l], b = r4[l + 64];
  float s = a.x*a.x + a.y*a.y + a.z*a.z + a.w*a.w
          + b.x*b.x + b.y*b.y + b.z*b.z + b.w*b.w;
#pragma unroll
  for (int off = 32; off; off >>= 1) s += __shfl_xor(s, off, 64);
  const float inv = 1.0f / (sqrtf(s) + 1e-12f);
  a.x *= inv; a.y *= inv; a.z *= inv; a.w *= inv;
  b.x *= inv; b.y *= inv; b.z *= inv; b.w *= inv;
  float4* o4 = (float4*)(outf + row * DIM);
  o4[l] = a; o4[l + 64] = b;
  int2 pa, pb;
  pa.x = (f2bf(a.x) & 0xFFFF) | ((int)f2bf(a.y) << 16);
  pa.y = (f2bf(a.z) & 0xFFFF) | ((int)f2bf(a.w) << 16);
  pb.x = (f2bf(b.x) & 0xFFFF) | ((int)f2bf(b.y) << 16);
  pb.y = (f2bf(b.z) & 0xFFFF) | ((int)f2bf(b.w) << 16);
  ((int2*)(outb + row * DIM))[l]       = pa;
  ((int2*)(outb + row * DIM + 256))[l] = pb;
}

// ---------------- normalize img rows + FUSED exact-f32 tp logit + seg-min -----
__global__ __launch_bounds__(256) void normalize_img_tp_kernel(
    const float* __restrict__ in, float* __restrict__ outf,
    short* __restrict__ outb, const float* __restrict__ ztxt,
    const int* __restrict__ key, unsigned long long* __restrict__ packed,
    const float* __restrict__ logt_p, const float* __restrict__ bias_p) {
  const int w = threadIdx.x >> 6, l = threadIdx.x & 63;
  const size_t row = (size_t)blockIdx.x * 4 + w;
  const float4* r4 = (const float4*)(in + row * DIM);
  float4 a = r4[l], b = r4[l + 64];
  float s = a.x*a.x + a.y*a.y + a.z*a.z + a.w*a.w
          + b.x*b.x + b.y*b.y + b.z*b.z + b.w*b.w;
#pragma unroll
  for (int off = 32; off; off >>= 1) s += __shfl_xor(s, off, 64);
  const float inv = 1.0f / (sqrtf(s) + 1e-12f);
  a.x *= inv; a.y *= inv; a.z *= inv; a.w *= inv;
  b.x *= inv; b.y *= inv; b.z *= inv; b.w *= inv;
  float4* o4 = (float4*)(outf + row * DIM);
  o4[l] = a; o4[l + 64] = b;
  int2 pa, pb;
  pa.x = (f2bf(a.x) & 0xFFFF) | ((int)f2bf(a.y) << 16);
  pa.y = (f2bf(a.z) & 0xFFFF) | ((int)f2bf(a.w) << 16);
  pb.x = (f2bf(b.x) & 0xFFFF) | ((int)f2bf(b.y) << 16);
  pb.y = (f2bf(b.z) & 0xFFFF) | ((int)f2bf(b.w) << 16);
  ((int2*)(outb + row * DIM))[l]       = pa;
  ((int2*)(outb + row * DIM + 256))[l] = pb;

  // fused true-positive logit (exact f32 path, identical to old tp_select)
  const int k = key[row];
  const float4* zt = (const float4*)(ztxt + (size_t)k * DIM);
  float4 c0 = zt[l], c1 = zt[l + 64];
  float d = a.x*c0.x + a.y*c0.y + a.z*c0.z + a.w*c0.w
          + b.x*c1.x + b.y*c1.y + b.z*c1.z + b.w*c1.w;
#pragma unroll
  for (int off = 32; off; off >>= 1) d += __shfl_xor(d, off, 64);
  if (l == 0) {
    const float t  = expf(logt_p[0]);
    const float tp = d * t + bias_p[0];
    const float loss = softplus_f(-tp);          // > 0 -> float bit order = value order
    const unsigned long long p =
        ((unsigned long long)__float_as_uint(loss) << 32) | (unsigned)row;
    atomicMin(&packed[k], p);                    // lexicographic (loss, index)
  }
}

// ---------------- select winners, gather bf16 rows (zero if no image) --------
__global__ __launch_bounds__(256) void gather_kernel(
    const unsigned long long* __restrict__ packed, float* __restrict__ out_idx,
    const short* __restrict__ zimgb, short* __restrict__ zselb) {
  const int w = threadIdx.x >> 6, l = threadIdx.x & 63;
  const int n = blockIdx.x * 4 + w;
  const unsigned long long p = packed[n];
  int4 v = {0, 0, 0, 0};
  float f = -1.0f;
  if (p != 0xFFFFFFFFFFFFFFFFull) {
    const int sel = (int)(p & 0xFFFFFFFFull);
    f = (float)sel;
    v = ((const int4*)(zimgb + (size_t)sel * DIM))[l];
  }
  ((int4*)(zselb + (size_t)n * DIM))[l] = v;
  if (l == 0) out_idx[n] = f;
}

// ---------------- merged bf16 MFMA GEMM, 256x256 tile, 3-ring counted-vmcnt ----
// by < 64 : C_ap = zimg * ztxt^T * t + b          (no loss)
// by >= 64: C_fl = zsel * ztxt^T * t + b, fused loss
// 8 waves (512 thr) as 2x4; per-wave output 128x64 -> acc[8][4].
// BK=32; 3-deep LDS ring (3 x 32KB = 96 KiB). Per-tile schedule:
//   vmcnt(8) gate (tile T's loads done; T+1,T+2 stay in flight)
//   barrier                      -- all waves' portions of slot T present
//   12 x ds_read_b128 (all af/bq fragments for the tile)
//   lgkmcnt(0) + sched_barrier   -- reads landed; slot T dead for this wave
//   barrier                      -- slot T dead for ALL waves
//   stage(T+3) into slot T%3     -- safe: slot dead; DMAs fly under MFMA
//   setprio(1); 32 MFMA; setprio(0)
// In-flight DMAs only ever target slots != the slot being read.
// PLAIN stores (not nontemporal): L2 absorbs the C stream; round-1's nt
// stores doubled HBM write traffic and serialized block turnover at 1 blk/CU.
__global__ __launch_bounds__(512, 2) void gemm_merged(
    const short* __restrict__ Aimg, const short* __restrict__ Asel,
    const short* __restrict__ B, float* __restrict__ Cap,
    float* __restrict__ Cfl, const float* __restrict__ logt_p,
    const float* __restrict__ bias_p, float* __restrict__ loss_out) {
  __shared__ alignas(16) short As[3][8192];   // 3 x 256x32 bf16 = 48 KiB
  __shared__ alignas(16) short Bs[3][8192];   // 48 KiB
  __shared__ float red[8];

  const int t  = threadIdx.x;
  const int w  = t >> 6, l = t & 63;
  const int wm = w >> 2, wn = w & 3;          // 2 x 4 wave grid
  const int fr = l & 15, quad = l >> 4;

  // XCD-aware bijective remap: 1280 blocks, 8 XCDs, 160/XCD, x-fastest chunk.
  int lin = blockIdx.y * 16 + blockIdx.x;
  lin = (lin & 7) * 160 + (lin >> 3);
  const int bx = lin & 15, by = lin >> 4;

  const bool fuse = (by >= 64);
  const int bm = (fuse ? by - 64 : by) << 8;
  const int bn = bx << 8;
  const short* A = fuse ? Asel : Aimg;
  float* C = fuse ? Cfl : Cap;

  // staging: thread t covers (row = t>>2 [+128 for site1], phys chunk = t&3);
  // global side reads logical chunk = (t&3) ^ (row&3)  (row&3 invariant +128)
  const int srow   = t >> 2;
  const int schunk = ((t & 3) ^ (srow & 3)) << 3;               // shorts
  const short* Ag = A + (size_t)(bm + srow) * KDIM + schunk;
  const short* Bg = B + (size_t)(bn + srow) * KDIM + schunk;
  const int sdst = w << 9;                                      // wave-uniform

  // ds_read side: logical chunk quad -> phys chunk quad ^ (fr&3)
  const int rchunk = (quad ^ (fr & 3)) << 3;                    // shorts
  const int abase = (wm * 128 + fr) * 32 + rchunk;
  const int bbase = (wn * 64 + fr) * 32 + rchunk;

  f32x4 acc[8][4] = {};

  auto stage = [&](int tile) {
    const int p = tile % 3;
    const int k0 = tile << 5;                                   // shorts
    const short* ga = Ag + k0;
    const short* gb = Bg + k0;
    short* la = &As[p][sdst];
    short* lb = &Bs[p][sdst];
    __builtin_amdgcn_global_load_lds(
        (const __attribute__((address_space(1))) void*)ga,
        (__attribute__((address_space(3))) void*)la, 16, 0, 0);
    __builtin_amdgcn_global_load_lds(
        (const __attribute__((address_space(1))) void*)(ga + (size_t)128 * KDIM),
        (__attribute__((address_space(3))) void*)(la + 4096), 16, 0, 0);
    __builtin_amdgcn_global_load_lds(
        (const __attribute__((address_space(1))) void*)gb,
        (__attribute__((address_space(3))) void*)lb, 16, 0, 0);
    __builtin_amdgcn_global_load_lds(
        (const __attribute__((address_space(1))) void*)(gb + (size_t)128 * KDIM),
        (__attribute__((address_space(3))) void*)(lb + 4096), 16, 0, 0);
  };

  // prologue: 3 tiles (12 loads/wave) in flight
  stage(0); stage(1); stage(2);

  // Ledger (per wave, 4 loads/tile): enter tile T with {T,T+1,T+2} in flight
  // (12); vmcnt(8) drains exactly tile T; stage(T+3) refills to 12.
  // Tail: T=14 enters with 8 -> vmcnt(4); T=15 enters with 4 -> vmcnt(0).
#define TILE(T, WN)                                                           \
  {                                                                           \
    asm volatile("s_waitcnt vmcnt(" #WN ")" ::: "memory");                    \
    __builtin_amdgcn_s_barrier();                                             \
    const short* Ab = &As[(T) % 3][abase];                                    \
    const short* Bb = &Bs[(T) % 3][bbase];                                    \
    bf16x8 af[8], bq[4];                                                      \
    _Pragma("unroll")                                                         \
    for (int mi = 0; mi < 8; ++mi) af[mi] = *(const bf16x8*)(Ab + mi * 512);  \
    _Pragma("unroll")                                                         \
    for (int nj = 0; nj < 4; ++nj) bq[nj] = *(const bf16x8*)(Bb + nj * 512);  \
    asm volatile("s_waitcnt lgkmcnt(0)" ::: "memory");                        \
    __builtin_amdgcn_sched_barrier(0);                                        \
    __builtin_amdgcn_s_barrier();                                             \
    if ((T) + 3 < 16) stage((T) + 3);                                         \
    __builtin_amdgcn_s_setprio(1);                                            \
    _Pragma("unroll")                                                         \
    for (int mi = 0; mi < 8; ++mi)                                            \
      _Pragma("unroll")                                                       \
      for (int nj = 0; nj < 4; ++nj)                                          \
        acc[mi][nj] = __builtin_amdgcn_mfma_f32_16x16x32_bf16(                \
            af[mi], bq[nj], acc[mi][nj], 0, 0, 0);                            \
    __builtin_amdgcn_s_setprio(0);                                            \
  }

#pragma unroll
  for (int T = 0; T < 14; ++T) TILE(T, 8)
  TILE(14, 4)
  TILE(15, 0)
#undef TILE

  const float tt = expf(logt_p[0]);
  const float bb = bias_p[0];
  float lsum = 0.0f;
#pragma unroll
  for (int mi = 0; mi < 8; ++mi) {
#pragma unroll
    for (int nj = 0; nj < 4; ++nj) {
      const int grow0 = bm + wm * 128 + mi * 16 + quad * 4;
      const int gcol  = bn + wn * 64 + nj * 16 + fr;
      f32x4 a = acc[mi][nj];
#pragma unroll
      for (int r = 0; r < 4; ++r) {
        const float v = a[r] * tt + bb;
        C[(size_t)(grow0 + r) * N_TXT + gcol] = v;
        if (fuse) {
          const float lab = (grow0 + r == gcol) ? 1.0f : -1.0f;
          lsum += softplus_f(-lab * v);
        }
      }
    }
  }
  if (fuse) {
#pragma unroll
    for (int off = 32; off; off >>= 1) lsum += __shfl_xor(lsum, off, 64);
    if (l == 0) red[w] = lsum;
    __syncthreads();
    if (t == 0) {
      float s2 = 0.0f;
#pragma unroll
      for (int i = 0; i < 8; ++i) s2 += red[i];
      atomicAdd(loss_out, s2 * (1.0f / N_TXT));
    }
  }
}

// ---------------- launch --------------------------------------------------------
extern "C" void kernel_launch(void* const* d_in, const int* in_sizes, int n_in,
                              void* d_out, int out_size, void* d_ws, size_t ws_size,
                              hipStream_t stream) {
  const float* img  = (const float*)d_in[0];
  const float* txt  = (const float*)d_in[1];
  const int*   key  = (const int*)d_in[2];
  const float* logt = (const float*)d_in[3];
  const float* bias = (const float*)d_in[4];

  float* out    = (float*)d_out;
  float* o_loss = out;                                   // [1]
  float* o_sel  = out + 1;                               // [N]
  float* o_zimg = o_sel + N_TXT;                         // [S, 512]
  float* o_ztxt = o_zimg + (size_t)S_IMG * DIM;          // [N, 512]
  float* o_ap   = o_ztxt + (size_t)N_TXT * DIM;          // [S, N]
  float* o_fl   = o_ap + (size_t)S_IMG * N_TXT;          // [N, N]

  char* ws = (char*)d_ws;
  short* zimgb = (short*)ws;                                         // 16 MB
  short* ztxtb = (short*)(ws + (size_t)S_IMG * DIM * 2);             //  4 MB
  short* zselb = (short*)(ws + (size_t)(S_IMG + N_TXT) * DIM * 2);   //  4 MB
  unsigned long long* packed =
      (unsigned long long*)(ws + (size_t)(S_IMG + 2 * N_TXT) * DIM * 2);

  init_kernel<<<N_TXT / 256, 256, 0, stream>>>(packed, o_loss);
  normalize_kernel<<<N_TXT / 4, 256, 0, stream>>>(txt, o_ztxt, ztxtb);
  normalize_img_tp_kernel<<<S_IMG / 4, 256, 0, stream>>>(
      img, o_zimg, zimgb, o_ztxt, key, packed, logt, bias);
  gather_kernel<<<N_TXT / 4, 256, 0, stream>>>(packed, o_sel, zimgb, zselb);
  gemm_merged<<<dim3(N_TXT / 256, S_IMG / 256 + N_TXT / 256), 512, 0, stream>>>(
      zimgb, zselb, ztxtb, o_ap, o_fl, logt, bias, o_loss);
}

// Round 3
// 766.069 us; speedup vs baseline: 1.0006x; 1.0006x over previous
//
#include <hip/hip_runtime.h>
#include <hip/hip_bf16.h>

#define S_IMG 16384
#define N_TXT 4096
#define DIM   512
#define KDIM  512

typedef __attribute__((ext_vector_type(8))) short bf16x8;
typedef __attribute__((ext_vector_type(4))) float f32x4;

__device__ __forceinline__ short f2bf(float f) {
  unsigned u = __float_as_uint(f);
  u += 0x7FFFu + ((u >> 16) & 1u);   // RNE
  return (short)(u >> 16);
}

__device__ __forceinline__ float softplus_f(float x) {
  return fmaxf(x, 0.0f) + log1pf(expf(-fabsf(x)));
}

// ---------------- init: sentinel for segment-min, zero the loss accumulator ----
__global__ __launch_bounds__(256) void init_kernel(
    unsigned long long* __restrict__ packed, float* __restrict__ out_loss) {
  const int i = blockIdx.x * 256 + threadIdx.x;
  packed[i] = 0xFFFFFFFFFFFFFFFFull;
  if (i == 0) out_loss[0] = 0.0f;
}

// ---------------- L2 normalize rows (txt), emit f32 (output) + bf16 (MFMA) ----
__global__ __launch_bounds__(256) void normalize_kernel(
    const float* __restrict__ in, float* __restrict__ outf,
    short* __restrict__ outb) {
  const int w = threadIdx.x >> 6, l = threadIdx.x & 63;
  const size_t row = (size_t)blockIdx.x * 4 + w;
  const float4* r4 = (const float4*)(in + row * DIM);
  float4 a = r4[l], b = r4[l + 64];
  float s = a.x*a.x + a.y*a.y + a.z*a.z + a.w*a.w
          + b.x*b.x + b.y*b.y + b.z*b.z + b.w*b.w;
#pragma unroll
  for (int off = 32; off; off >>= 1) s += __shfl_xor(s, off, 64);
  const float inv = 1.0f / (sqrtf(s) + 1e-12f);
  a.x *= inv; a.y *= inv; a.z *= inv; a.w *= inv;
  b.x *= inv; b.y *= inv; b.z *= inv; b.w *= inv;
  float4* o4 = (float4*)(outf + row * DIM);
  o4[l] = a; o4[l + 64] = b;
  int2 pa, pb;
  pa.x = (f2bf(a.x) & 0xFFFF) | ((int)f2bf(a.y) << 16);
  pa.y = (f2bf(a.z) & 0xFFFF) | ((int)f2bf(a.w) << 16);
  pb.x = (f2bf(b.x) & 0xFFFF) | ((int)f2bf(b.y) << 16);
  pb.y = (f2bf(b.z) & 0xFFFF) | ((int)f2bf(b.w) << 16);
  ((int2*)(outb + row * DIM))[l]       = pa;
  ((int2*)(outb + row * DIM + 256))[l] = pb;
}

// ---------------- normalize img rows + FUSED exact-f32 tp logit + seg-min -----
__global__ __launch_bounds__(256) void normalize_img_tp_kernel(
    const float* __restrict__ in, float* __restrict__ outf,
    short* __restrict__ outb, const float* __restrict__ ztxt,
    const int* __restrict__ key, unsigned long long* __restrict__ packed,
    const float* __restrict__ logt_p, const float* __restrict__ bias_p) {
  const int w = threadIdx.x >> 6, l = threadIdx.x & 63;
  const size_t row = (size_t)blockIdx.x * 4 + w;
  const float4* r4 = (const float4*)(in + row * DIM);
  float4 a = r4[l], b = r4[l + 64];
  float s = a.x*a.x + a.y*a.y + a.z*a.z + a.w*a.w
          + b.x*b.x + b.y*b.y + b.z*b.z + b.w*b.w;
#pragma unroll
  for (int off = 32; off; off >>= 1) s += __shfl_xor(s, off, 64);
  const float inv = 1.0f / (sqrtf(s) + 1e-12f);
  a.x *= inv; a.y *= inv; a.z *= inv; a.w *= inv;
  b.x *= inv; b.y *= inv; b.z *= inv; b.w *= inv;
  float4* o4 = (float4*)(outf + row * DIM);
  o4[l] = a; o4[l + 64] = b;
  int2 pa, pb;
  pa.x = (f2bf(a.x) & 0xFFFF) | ((int)f2bf(a.y) << 16);
  pa.y = (f2bf(a.z) & 0xFFFF) | ((int)f2bf(a.w) << 16);
  pb.x = (f2bf(b.x) & 0xFFFF) | ((int)f2bf(b.y) << 16);
  pb.y = (f2bf(b.z) & 0xFFFF) | ((int)f2bf(b.w) << 16);
  ((int2*)(outb + row * DIM))[l]       = pa;
  ((int2*)(outb + row * DIM + 256))[l] = pb;

  // fused true-positive logit (exact f32 path, identical to old tp_select)
  const int k = key[row];
  const float4* zt = (const float4*)(ztxt + (size_t)k * DIM);
  float4 c0 = zt[l], c1 = zt[l + 64];
  float d = a.x*c0.x + a.y*c0.y + a.z*c0.z + a.w*c0.w
          + b.x*c1.x + b.y*c1.y + b.z*c1.z + b.w*c1.w;
#pragma unroll
  for (int off = 32; off; off >>= 1) d += __shfl_xor(d, off, 64);
  if (l == 0) {
    const float t  = expf(logt_p[0]);
    const float tp = d * t + bias_p[0];
    const float loss = softplus_f(-tp);          // > 0 -> float bit order = value order
    const unsigned long long p =
        ((unsigned long long)__float_as_uint(loss) << 32) | (unsigned)row;
    atomicMin(&packed[k], p);                    // lexicographic (loss, index)
  }
}

// ---------------- select winners, gather bf16 rows (zero if no image) --------
__global__ __launch_bounds__(256) void gather_kernel(
    const unsigned long long* __restrict__ packed, float* __restrict__ out_idx,
    const short* __restrict__ zimgb, short* __restrict__ zselb) {
  const int w = threadIdx.x >> 6, l = threadIdx.x & 63;
  const int n = blockIdx.x * 4 + w;
  const unsigned long long p = packed[n];
  int4 v = {0, 0, 0, 0};
  float f = -1.0f;
  if (p != 0xFFFFFFFFFFFFFFFFull) {
    const int sel = (int)(p & 0xFFFFFFFFull);
    f = (float)sel;
    v = ((const int4*)(zimgb + (size_t)sel * DIM))[l];
  }
  ((int4*)(zselb + (size_t)n * DIM))[l] = v;
  if (l == 0) out_idx[n] = f;
}

// ---------------- merged bf16 MFMA GEMM: 256x256 tile, BK=64, 2-phase recipe ---
// The catalog's measured "minimum 2-phase" structure (682-745 TF @256²):
//   prologue: STAGE(buf0, tile0); vmcnt(0); barrier
//   per K-tile: STAGE(buf^1, next) FIRST; ds_read cur; lgkm(0); MFMA;
//               vmcnt(0); s_barrier; flip.
// BK=64 => 128-B rows: each global_load_lds covers 8 rows x 128 B = full
// L2 lines (r2's BK=32 scattered 64-B half-lines at 2x the request count and
// measured a 1.5 TB/s staging wall).
// Swizzle: 16-B chunk ^= (row & 7) -- full 8-way spread: a ds_read_b128
// 16-lane pass covers all 32 banks 2-way (free, m136). Applied inverse on the
// GLOBAL source (gload_lds dest must be lane-linear) and on the ds_read addr.
// K-accumulation order identical to r2 (k=0..511 in 32-steps) -> same absmax.
__global__ __launch_bounds__(512, 2) void gemm_merged(
    const short* __restrict__ Aimg, const short* __restrict__ Asel,
    const short* __restrict__ B, float* __restrict__ Cap,
    float* __restrict__ Cfl, const float* __restrict__ logt_p,
    const float* __restrict__ bias_p, float* __restrict__ loss_out) {
  __shared__ alignas(16) short As[2][16384];   // 2 x 256x64 bf16 = 64 KiB
  __shared__ alignas(16) short Bs[2][16384];   // 64 KiB
  __shared__ float red[8];

  const int t  = threadIdx.x;
  const int w  = t >> 6, l = t & 63;
  const int wm = w >> 2, wn = w & 3;          // 2 x 4 wave grid
  const int fr = l & 15, quad = l >> 4;

  // XCD-aware bijective remap: 1280 blocks, 8 XCDs, 160/XCD, x-fastest chunk.
  int lin = blockIdx.y * 16 + blockIdx.x;
  lin = (lin & 7) * 160 + (lin >> 3);
  const int bx = lin & 15, by = lin >> 4;

  const bool fuse = (by >= 64);
  const int bm = (fuse ? by - 64 : by) << 8;
  const int bn = bx << 8;
  const short* A = fuse ? Asel : Aimg;
  float* C = fuse ? Cfl : Cap;

  // staging geometry: thread t covers rows (t>>3)+{0,64,128,192}, phys 16-B
  // chunk (t&7). Global logical chunk = (t&7) ^ (row&7); row&7 == (t>>3)&7
  // for all 4 sub-loads (64 % 8 == 0). Dest chunk linear index = t + j*512
  // -> byte = t*16 + j*8192: wave-uniform base (w*1024 + j*8192) + lane*16.
  const int srow = t >> 3;
  const int sc   = (t & 7) ^ (srow & 7);
  const short* Ag = A + (size_t)(bm + srow) * KDIM + sc * 8;
  const short* Bg = B + (size_t)(bn + srow) * KDIM + sc * 8;

  // ds_read side: logical chunk q at row -> phys chunk q ^ (row&7);
  // row&7 == fr&7 for both LDA (wm*128+mi*16+fr) and LDB (wn*64+nj*16+fr).
  const int cx = fr & 7;

  f32x4 acc[8][4] = {};

  auto stage = [&](int tile, int buf) {
    const int k0 = tile << 6;                                   // shorts
#pragma unroll
    for (int j = 0; j < 4; ++j) {
      const short* ga = Ag + (size_t)(j * 64) * KDIM + k0;
      const short* gb = Bg + (size_t)(j * 64) * KDIM + k0;
      __builtin_amdgcn_global_load_lds(
          (const __attribute__((address_space(1))) void*)ga,
          (__attribute__((address_space(3))) void*)(&As[buf][(w << 9) + j * 4096]),
          16, 0, 0);
      __builtin_amdgcn_global_load_lds(
          (const __attribute__((address_space(1))) void*)gb,
          (__attribute__((address_space(3))) void*)(&Bs[buf][(w << 9) + j * 4096]),
          16, 0, 0);
    }
  };

  // prologue: tile 0 into buf 0, full drain, barrier
  stage(0, 0);
  asm volatile("s_waitcnt vmcnt(0)" ::: "memory");
  __builtin_amdgcn_s_barrier();

#pragma unroll
  for (int T = 0; T < 8; ++T) {
    const int cur = T & 1;
    if (T < 7) stage(T + 1, cur ^ 1);           // issue next-tile loads FIRST
    const short* Ab = &As[cur][(wm * 128 + fr) * 64];
    const short* Bb = &Bs[cur][(wn * 64 + fr) * 64];
    bf16x8 af[8], bq[4];
#pragma unroll
    for (int kk = 0; kk < 2; ++kk) {
      const int ck = (((kk << 2) | quad) ^ cx) << 3;            // shorts
#pragma unroll
      for (int mi = 0; mi < 8; ++mi) af[mi] = *(const bf16x8*)(Ab + mi * 1024 + ck);
#pragma unroll
      for (int nj = 0; nj < 4; ++nj) bq[nj] = *(const bf16x8*)(Bb + nj * 1024 + ck);
      asm volatile("s_waitcnt lgkmcnt(0)" ::: "memory");
      __builtin_amdgcn_sched_barrier(0);
      __builtin_amdgcn_s_setprio(1);
#pragma unroll
      for (int mi = 0; mi < 8; ++mi)
#pragma unroll
        for (int nj = 0; nj < 4; ++nj)
          acc[mi][nj] = __builtin_amdgcn_mfma_f32_16x16x32_bf16(
              af[mi], bq[nj], acc[mi][nj], 0, 0, 0);
      __builtin_amdgcn_s_setprio(0);
    }
    asm volatile("s_waitcnt vmcnt(0)" ::: "memory");
    __builtin_amdgcn_s_barrier();
  }

  const float tt = expf(logt_p[0]);
  const float bb = bias_p[0];
  float lsum = 0.0f;
#pragma unroll
  for (int mi = 0; mi < 8; ++mi) {
#pragma unroll
    for (int nj = 0; nj < 4; ++nj) {
      const int grow0 = bm + wm * 128 + mi * 16 + quad * 4;
      const int gcol  = bn + wn * 64 + nj * 16 + fr;
      f32x4 a = acc[mi][nj];
#pragma unroll
      for (int r = 0; r < 4; ++r) {
        const float v = a[r] * tt + bb;
        C[(size_t)(grow0 + r) * N_TXT + gcol] = v;
        if (fuse) {
          const float lab = (grow0 + r == gcol) ? 1.0f : -1.0f;
          lsum += softplus_f(-lab * v);
        }
      }
    }
  }
  if (fuse) {
#pragma unroll
    for (int off = 32; off; off >>= 1) lsum += __shfl_xor(lsum, off, 64);
    if (l == 0) red[w] = lsum;
    __syncthreads();
    if (t == 0) {
      float s2 = 0.0f;
#pragma unroll
      for (int i = 0; i < 8; ++i) s2 += red[i];
      atomicAdd(loss_out, s2 * (1.0f / N_TXT));
    }
  }
}

// ---------------- launch --------------------------------------------------------
extern "C" void kernel_launch(void* const* d_in, const int* in_sizes, int n_in,
                              void* d_out, int out_size, void* d_ws, size_t ws_size,
                              hipStream_t stream) {
  const float* img  = (const float*)d_in[0];
  const float* txt  = (const float*)d_in[1];
  const int*   key  = (const int*)d_in[2];
  const float* logt = (const float*)d_in[3];
  const float* bias = (const float*)d_in[4];

  float* out    = (float*)d_out;
  float* o_loss = out;                                   // [1]
  float* o_sel  = out + 1;                               // [N]
  float* o_zimg = o_sel + N_TXT;                         // [S, 512]
  float* o_ztxt = o_zimg + (size_t)S_IMG * DIM;          // [N, 512]
  float* o_ap   = o_ztxt + (size_t)N_TXT * DIM;          // [S, N]
  float* o_fl   = o_ap + (size_t)S_IMG * N_TXT;          // [N, N]

  char* ws = (char*)d_ws;
  short* zimgb = (short*)ws;                                         // 16 MB
  short* ztxtb = (short*)(ws + (size_t)S_IMG * DIM * 2);             //  4 MB
  short* zselb = (short*)(ws + (size_t)(S_IMG + N_TXT) * DIM * 2);   //  4 MB
  unsigned long long* packed =
      (unsigned long long*)(ws + (size_t)(S_IMG + 2 * N_TXT) * DIM * 2);

  init_kernel<<<N_TXT / 256, 256, 0, stream>>>(packed, o_loss);
  normalize_kernel<<<N_TXT / 4, 256, 0, stream>>>(txt, o_ztxt, ztxtb);
  normalize_img_tp_kernel<<<S_IMG / 4, 256, 0, stream>>>(
      img, o_zimg, zimgb, o_ztxt, key, packed, logt, bias);
  gather_kernel<<<N_TXT / 4, 256, 0, stream>>>(packed, o_sel, zimgb, zselb);
  gemm_merged<<<dim3(N_TXT / 256, S_IMG / 256 + N_TXT / 256), 512, 0, stream>>>(
      zimgb, zselb, ztxtb, o_ap, o_fl, logt, bias, o_loss);
}

// Round 4
// 763.017 us; speedup vs baseline: 1.0046x; 1.0040x over previous
//
#include <hip/hip_runtime.h>
#include <hip/hip_bf16.h>

#define S_IMG 16384
#define N_TXT 4096
#define DIM   512
#define KDIM  512

typedef __attribute__((ext_vector_type(8))) short bf16x8;
typedef __attribute__((ext_vector_type(4))) float f32x4;

__device__ __forceinline__ short f2bf(float f) {
  unsigned u = __float_as_uint(f);
  u += 0x7FFFu + ((u >> 16) & 1u);   // RNE
  return (short)(u >> 16);
}

__device__ __forceinline__ float softplus_f(float x) {
  return fmaxf(x, 0.0f) + log1pf(expf(-fabsf(x)));
}

// ---------------- init: sentinel for segment-min, zero the loss accumulator ----
__global__ __launch_bounds__(256) void init_kernel(
    unsigned long long* __restrict__ packed, float* __restrict__ out_loss) {
  const int i = blockIdx.x * 256 + threadIdx.x;
  packed[i] = 0xFFFFFFFFFFFFFFFFull;
  if (i == 0) out_loss[0] = 0.0f;
}

// ---------------- L2 normalize rows (txt), emit f32 (output) + bf16 (MFMA) ----
__global__ __launch_bounds__(256) void normalize_kernel(
    const float* __restrict__ in, float* __restrict__ outf,
    short* __restrict__ outb) {
  const int w = threadIdx.x >> 6, l = threadIdx.x & 63;
  const size_t row = (size_t)blockIdx.x * 4 + w;
  const float4* r4 = (const float4*)(in + row * DIM);
  float4 a = r4[l], b = r4[l + 64];
  float s = a.x*a.x + a.y*a.y + a.z*a.z + a.w*a.w
          + b.x*b.x + b.y*b.y + b.z*b.z + b.w*b.w;
#pragma unroll
  for (int off = 32; off; off >>= 1) s += __shfl_xor(s, off, 64);
  const float inv = 1.0f / (sqrtf(s) + 1e-12f);
  a.x *= inv; a.y *= inv; a.z *= inv; a.w *= inv;
  b.x *= inv; b.y *= inv; b.z *= inv; b.w *= inv;
  float4* o4 = (float4*)(outf + row * DIM);
  o4[l] = a; o4[l + 64] = b;
  int2 pa, pb;
  pa.x = (f2bf(a.x) & 0xFFFF) | ((int)f2bf(a.y) << 16);
  pa.y = (f2bf(a.z) & 0xFFFF) | ((int)f2bf(a.w) << 16);
  pb.x = (f2bf(b.x) & 0xFFFF) | ((int)f2bf(b.y) << 16);
  pb.y = (f2bf(b.z) & 0xFFFF) | ((int)f2bf(b.w) << 16);
  ((int2*)(outb + row * DIM))[l]       = pa;
  ((int2*)(outb + row * DIM + 256))[l] = pb;
}

// ---------------- normalize img rows + FUSED exact-f32 tp logit + seg-min -----
__global__ __launch_bounds__(256) void normalize_img_tp_kernel(
    const float* __restrict__ in, float* __restrict__ outf,
    short* __restrict__ outb, const float* __restrict__ ztxt,
    const int* __restrict__ key, unsigned long long* __restrict__ packed,
    const float* __restrict__ logt_p, const float* __restrict__ bias_p) {
  const int w = threadIdx.x >> 6, l = threadIdx.x & 63;
  const size_t row = (size_t)blockIdx.x * 4 + w;
  const float4* r4 = (const float4*)(in + row * DIM);
  float4 a = r4[l], b = r4[l + 64];
  float s = a.x*a.x + a.y*a.y + a.z*a.z + a.w*a.w
          + b.x*b.x + b.y*b.y + b.z*b.z + b.w*b.w;
#pragma unroll
  for (int off = 32; off; off >>= 1) s += __shfl_xor(s, off, 64);
  const float inv = 1.0f / (sqrtf(s) + 1e-12f);
  a.x *= inv; a.y *= inv; a.z *= inv; a.w *= inv;
  b.x *= inv; b.y *= inv; b.z *= inv; b.w *= inv;
  float4* o4 = (float4*)(outf + row * DIM);
  o4[l] = a; o4[l + 64] = b;
  int2 pa, pb;
  pa.x = (f2bf(a.x) & 0xFFFF) | ((int)f2bf(a.y) << 16);
  pa.y = (f2bf(a.z) & 0xFFFF) | ((int)f2bf(a.w) << 16);
  pb.x = (f2bf(b.x) & 0xFFFF) | ((int)f2bf(b.y) << 16);
  pb.y = (f2bf(b.z) & 0xFFFF) | ((int)f2bf(b.w) << 16);
  ((int2*)(outb + row * DIM))[l]       = pa;
  ((int2*)(outb + row * DIM + 256))[l] = pb;

  // fused true-positive logit (exact f32 path, identical to old tp_select)
  const int k = key[row];
  const float4* zt = (const float4*)(ztxt + (size_t)k * DIM);
  float4 c0 = zt[l], c1 = zt[l + 64];
  float d = a.x*c0.x + a.y*c0.y + a.z*c0.z + a.w*c0.w
          + b.x*c1.x + b.y*c1.y + b.z*c1.z + b.w*c1.w;
#pragma unroll
  for (int off = 32; off; off >>= 1) d += __shfl_xor(d, off, 64);
  if (l == 0) {
    const float t  = expf(logt_p[0]);
    const float tp = d * t + bias_p[0];
    const float loss = softplus_f(-tp);          // > 0 -> float bit order = value order
    const unsigned long long p =
        ((unsigned long long)__float_as_uint(loss) << 32) | (unsigned)row;
    atomicMin(&packed[k], p);                    // lexicographic (loss, index)
  }
}

// ---------------- select winners, gather bf16 rows (zero if no image) --------
__global__ __launch_bounds__(256) void gather_kernel(
    const unsigned long long* __restrict__ packed, float* __restrict__ out_idx,
    const short* __restrict__ zimgb, short* __restrict__ zselb) {
  const int w = threadIdx.x >> 6, l = threadIdx.x & 63;
  const int n = blockIdx.x * 4 + w;
  const unsigned long long p = packed[n];
  int4 v = {0, 0, 0, 0};
  float f = -1.0f;
  if (p != 0xFFFFFFFFFFFFFFFFull) {
    const int sel = (int)(p & 0xFFFFFFFFull);
    f = (float)sel;
    v = ((const int4*)(zimgb + (size_t)sel * DIM))[l];
  }
  ((int4*)(zselb + (size_t)n * DIM))[l] = v;
  if (l == 0) out_idx[n] = f;
}

// ---------------- merged bf16 MFMA GEMM: 256x256 tile, BK=64, 2-phase recipe ---
// Identical to round-3 EXCEPT the block->tile mapping (single-variable A/B).
// r1-r3 all hit a ~1.5 TB/s staging wall regardless of schedule: the old
// x-fastest XCD chunking made each XCD's 32 co-resident blocks span ALL 16
// column panels -> entire 4 MB B + A + C-stream > 4 MB L2 -> LRU thrash ->
// all staging crosses the fabric to L3 (~190 GB/s/XCD aggregate = the wall).
// New mapping: XCD k owns by in [k*10, k*10+10) (2.5 MB of A, L2-resident for
// the WHOLE kernel), traversed by-fastest so a temporal window of 32 blocks
// spans ~4 bx panels (1 MB of B). Working set 3.5 MB < 4 MB L2.
__global__ __launch_bounds__(512, 2) void gemm_merged(
    const short* __restrict__ Aimg, const short* __restrict__ Asel,
    const short* __restrict__ B, float* __restrict__ Cap,
    float* __restrict__ Cfl, const float* __restrict__ logt_p,
    const float* __restrict__ bias_p, float* __restrict__ loss_out) {
  __shared__ alignas(16) short As[2][16384];   // 2 x 256x64 bf16 = 64 KiB
  __shared__ alignas(16) short Bs[2][16384];   // 64 KiB
  __shared__ float red[8];

  const int t  = threadIdx.x;
  const int w  = t >> 6, l = t & 63;
  const int wm = w >> 2, wn = w & 3;          // 2 x 4 wave grid
  const int fr = l & 15, quad = l >> 4;

  // XCD-bijective, by-fastest within-XCD chunk (L2 working-set fix):
  // lin -> (xcd = lin&7, j = lin>>3 in [0,160));  bx = j/10, by = xcd*10 + j%10.
  // Bijection: 8 xcd x 16 bx x 10 byl = 1280 = gridDim.x*gridDim.y.
  const int lin = blockIdx.y * 16 + blockIdx.x;
  const int xcd = lin & 7;
  const int j   = lin >> 3;
  const int bx  = j / 10;
  const int by  = xcd * 10 + (j - bx * 10);

  const bool fuse = (by >= 64);
  const int bm = (fuse ? by - 64 : by) << 8;
  const int bn = bx << 8;
  const short* A = fuse ? Asel : Aimg;
  float* C = fuse ? Cfl : Cap;

  // staging geometry: thread t covers rows (t>>3)+{0,64,128,192}, phys 16-B
  // chunk (t&7). Global logical chunk = (t&7) ^ (row&7); row&7 == (t>>3)&7
  // for all 4 sub-loads (64 % 8 == 0). Dest chunk linear index = t + j*512
  // -> byte = t*16 + j*8192: wave-uniform base (w*1024 + j*8192) + lane*16.
  const int srow = t >> 3;
  const int sc   = (t & 7) ^ (srow & 7);
  const short* Ag = A + (size_t)(bm + srow) * KDIM + sc * 8;
  const short* Bg = B + (size_t)(bn + srow) * KDIM + sc * 8;

  // ds_read side: logical chunk q at row -> phys chunk q ^ (row&7);
  // row&7 == fr&7 for both LDA (wm*128+mi*16+fr) and LDB (wn*64+nj*16+fr).
  const int cx = fr & 7;

  f32x4 acc[8][4] = {};

  auto stage = [&](int tile, int buf) {
    const int k0 = tile << 6;                                   // shorts
#pragma unroll
    for (int jj = 0; jj < 4; ++jj) {
      const short* ga = Ag + (size_t)(jj * 64) * KDIM + k0;
      const short* gb = Bg + (size_t)(jj * 64) * KDIM + k0;
      __builtin_amdgcn_global_load_lds(
          (const __attribute__((address_space(1))) void*)ga,
          (__attribute__((address_space(3))) void*)(&As[buf][(w << 9) + jj * 4096]),
          16, 0, 0);
      __builtin_amdgcn_global_load_lds(
          (const __attribute__((address_space(1))) void*)gb,
          (__attribute__((address_space(3))) void*)(&Bs[buf][(w << 9) + jj * 4096]),
          16, 0, 0);
    }
  };

  // prologue: tile 0 into buf 0, full drain, barrier
  stage(0, 0);
  asm volatile("s_waitcnt vmcnt(0)" ::: "memory");
  __builtin_amdgcn_s_barrier();

#pragma unroll
  for (int T = 0; T < 8; ++T) {
    const int cur = T & 1;
    if (T < 7) stage(T + 1, cur ^ 1);           // issue next-tile loads FIRST
    const short* Ab = &As[cur][(wm * 128 + fr) * 64];
    const short* Bb = &Bs[cur][(wn * 64 + fr) * 64];
    bf16x8 af[8], bq[4];
#pragma unroll
    for (int kk = 0; kk < 2; ++kk) {
      const int ck = (((kk << 2) | quad) ^ cx) << 3;            // shorts
#pragma unroll
      for (int mi = 0; mi < 8; ++mi) af[mi] = *(const bf16x8*)(Ab + mi * 1024 + ck);
#pragma unroll
      for (int nj = 0; nj < 4; ++nj) bq[nj] = *(const bf16x8*)(Bb + nj * 1024 + ck);
      asm volatile("s_waitcnt lgkmcnt(0)" ::: "memory");
      __builtin_amdgcn_sched_barrier(0);
      __builtin_amdgcn_s_setprio(1);
#pragma unroll
      for (int mi = 0; mi < 8; ++mi)
#pragma unroll
        for (int nj = 0; nj < 4; ++nj)
          acc[mi][nj] = __builtin_amdgcn_mfma_f32_16x16x32_bf16(
              af[mi], bq[nj], acc[mi][nj], 0, 0, 0);
      __builtin_amdgcn_s_setprio(0);
    }
    asm volatile("s_waitcnt vmcnt(0)" ::: "memory");
    __builtin_amdgcn_s_barrier();
  }

  const float tt = expf(logt_p[0]);
  const float bb = bias_p[0];
  float lsum = 0.0f;
#pragma unroll
  for (int mi = 0; mi < 8; ++mi) {
#pragma unroll
    for (int nj = 0; nj < 4; ++nj) {
      const int grow0 = bm + wm * 128 + mi * 16 + quad * 4;
      const int gcol  = bn + wn * 64 + nj * 16 + fr;
      f32x4 a = acc[mi][nj];
#pragma unroll
      for (int r = 0; r < 4; ++r) {
        const float v = a[r] * tt + bb;
        C[(size_t)(grow0 + r) * N_TXT + gcol] = v;
        if (fuse) {
          const float lab = (grow0 + r == gcol) ? 1.0f : -1.0f;
          lsum += softplus_f(-lab * v);
        }
      }
    }
  }
  if (fuse) {
#pragma unroll
    for (int off = 32; off; off >>= 1) lsum += __shfl_xor(lsum, off, 64);
    if (l == 0) red[w] = lsum;
    __syncthreads();
    if (t == 0) {
      float s2 = 0.0f;
#pragma unroll
      for (int i = 0; i < 8; ++i) s2 += red[i];
      atomicAdd(loss_out, s2 * (1.0f / N_TXT));
    }
  }
}

// ---------------- launch --------------------------------------------------------
extern "C" void kernel_launch(void* const* d_in, const int* in_sizes, int n_in,
                              void* d_out, int out_size, void* d_ws, size_t ws_size,
                              hipStream_t stream) {
  const float* img  = (const float*)d_in[0];
  const float* txt  = (const float*)d_in[1];
  const int*   key  = (const int*)d_in[2];
  const float* logt = (const float*)d_in[3];
  const float* bias = (const float*)d_in[4];

  float* out    = (float*)d_out;
  float* o_loss = out;                                   // [1]
  float* o_sel  = out + 1;                               // [N]
  float* o_zimg = o_sel + N_TXT;                         // [S, 512]
  float* o_ztxt = o_zimg + (size_t)S_IMG * DIM;          // [N, 512]
  float* o_ap   = o_ztxt + (size_t)N_TXT * DIM;          // [S, N]
  float* o_fl   = o_ap + (size_t)S_IMG * N_TXT;          // [N, N]

  char* ws = (char*)d_ws;
  short* zimgb = (short*)ws;                                         // 16 MB
  short* ztxtb = (short*)(ws + (size_t)S_IMG * DIM * 2);             //  4 MB
  short* zselb = (short*)(ws + (size_t)(S_IMG + N_TXT) * DIM * 2);   //  4 MB
  unsigned long long* packed =
      (unsigned long long*)(ws + (size_t)(S_IMG + 2 * N_TXT) * DIM * 2);

  init_kernel<<<N_TXT / 256, 256, 0, stream>>>(packed, o_loss);
  normalize_kernel<<<N_TXT / 4, 256, 0, stream>>>(txt, o_ztxt, ztxtb);
  normalize_img_tp_kernel<<<S_IMG / 4, 256, 0, stream>>>(
      img, o_zimg, zimgb, o_ztxt, key, packed, logt, bias);
  gather_kernel<<<N_TXT / 4, 256, 0, stream>>>(packed, o_sel, zimgb, zselb);
  gemm_merged<<<dim3(N_TXT / 256, S_IMG / 256 + N_TXT / 256), 512, 0, stream>>>(
      zimgb, zselb, ztxtb, o_ap, o_fl, logt, bias, o_loss);
}

// Round 5
// 564.873 us; speedup vs baseline: 1.3570x; 1.3508x over previous
//
#include <hip/hip_runtime.h>
#include <hip/hip_bf16.h>

#define S_IMG 16384
#define N_TXT 4096
#define DIM   512
#define KDIM  512

typedef __attribute__((ext_vector_type(8))) short bf16x8;
typedef __attribute__((ext_vector_type(4))) float f32x4;

__device__ __forceinline__ short f2bf(float f) {
  unsigned u = __float_as_uint(f);
  u += 0x7FFFu + ((u >> 16) & 1u);   // RNE
  return (short)(u >> 16);
}

__device__ __forceinline__ float softplus_f(float x) {
  return fmaxf(x, 0.0f) + log1pf(expf(-fabsf(x)));
}

// ---------------- init: sentinel for segment-min, zero the loss accumulator ----
__global__ __launch_bounds__(256) void init_kernel(
    unsigned long long* __restrict__ packed, float* __restrict__ out_loss) {
  const int i = blockIdx.x * 256 + threadIdx.x;
  packed[i] = 0xFFFFFFFFFFFFFFFFull;
  if (i == 0) out_loss[0] = 0.0f;
}

// ---------------- L2 normalize rows (txt), emit f32 (output) + bf16 (MFMA) ----
__global__ __launch_bounds__(256) void normalize_kernel(
    const float* __restrict__ in, float* __restrict__ outf,
    short* __restrict__ outb) {
  const int w = threadIdx.x >> 6, l = threadIdx.x & 63;
  const size_t row = (size_t)blockIdx.x * 4 + w;
  const float4* r4 = (const float4*)(in + row * DIM);
  float4 a = r4[l], b = r4[l + 64];
  float s = a.x*a.x + a.y*a.y + a.z*a.z + a.w*a.w
          + b.x*b.x + b.y*b.y + b.z*b.z + b.w*b.w;
#pragma unroll
  for (int off = 32; off; off >>= 1) s += __shfl_xor(s, off, 64);
  const float inv = 1.0f / (sqrtf(s) + 1e-12f);
  a.x *= inv; a.y *= inv; a.z *= inv; a.w *= inv;
  b.x *= inv; b.y *= inv; b.z *= inv; b.w *= inv;
  float4* o4 = (float4*)(outf + row * DIM);
  o4[l] = a; o4[l + 64] = b;
  int2 pa, pb;
  pa.x = (f2bf(a.x) & 0xFFFF) | ((int)f2bf(a.y) << 16);
  pa.y = (f2bf(a.z) & 0xFFFF) | ((int)f2bf(a.w) << 16);
  pb.x = (f2bf(b.x) & 0xFFFF) | ((int)f2bf(b.y) << 16);
  pb.y = (f2bf(b.z) & 0xFFFF) | ((int)f2bf(b.w) << 16);
  ((int2*)(outb + row * DIM))[l]       = pa;
  ((int2*)(outb + row * DIM + 256))[l] = pb;
}

// ---------------- normalize img rows + FUSED exact-f32 tp logit + seg-min -----
// Verified in rounds 1-4 (passed, absmax unchanged). Saves a full 33.5 MB
// re-read of zimg f32 and one launch vs the separate tp_select kernel.
__global__ __launch_bounds__(256) void normalize_img_tp_kernel(
    const float* __restrict__ in, float* __restrict__ outf,
    short* __restrict__ outb, const float* __restrict__ ztxt,
    const int* __restrict__ key, unsigned long long* __restrict__ packed,
    const float* __restrict__ logt_p, const float* __restrict__ bias_p) {
  const int w = threadIdx.x >> 6, l = threadIdx.x & 63;
  const size_t row = (size_t)blockIdx.x * 4 + w;
  const float4* r4 = (const float4*)(in + row * DIM);
  float4 a = r4[l], b = r4[l + 64];
  float s = a.x*a.x + a.y*a.y + a.z*a.z + a.w*a.w
          + b.x*b.x + b.y*b.y + b.z*b.z + b.w*b.w;
#pragma unroll
  for (int off = 32; off; off >>= 1) s += __shfl_xor(s, off, 64);
  const float inv = 1.0f / (sqrtf(s) + 1e-12f);
  a.x *= inv; a.y *= inv; a.z *= inv; a.w *= inv;
  b.x *= inv; b.y *= inv; b.z *= inv; b.w *= inv;
  float4* o4 = (float4*)(outf + row * DIM);
  o4[l] = a; o4[l + 64] = b;
  int2 pa, pb;
  pa.x = (f2bf(a.x) & 0xFFFF) | ((int)f2bf(a.y) << 16);
  pa.y = (f2bf(a.z) & 0xFFFF) | ((int)f2bf(a.w) << 16);
  pb.x = (f2bf(b.x) & 0xFFFF) | ((int)f2bf(b.y) << 16);
  pb.y = (f2bf(b.z) & 0xFFFF) | ((int)f2bf(b.w) << 16);
  ((int2*)(outb + row * DIM))[l]       = pa;
  ((int2*)(outb + row * DIM + 256))[l] = pb;

  // fused true-positive logit (exact f32 path, identical to old tp_select)
  const int k = key[row];
  const float4* zt = (const float4*)(ztxt + (size_t)k * DIM);
  float4 c0 = zt[l], c1 = zt[l + 64];
  float d = a.x*c0.x + a.y*c0.y + a.z*c0.z + a.w*c0.w
          + b.x*c1.x + b.y*c1.y + b.z*c1.z + b.w*c1.w;
#pragma unroll
  for (int off = 32; off; off >>= 1) d += __shfl_xor(d, off, 64);
  if (l == 0) {
    const float t  = expf(logt_p[0]);
    const float tp = d * t + bias_p[0];
    const float loss = softplus_f(-tp);          // > 0 -> float bit order = value order
    const unsigned long long p =
        ((unsigned long long)__float_as_uint(loss) << 32) | (unsigned)row;
    atomicMin(&packed[k], p);                    // lexicographic (loss, index)
  }
}

// ---------------- select winners, gather bf16 rows (zero if no image) --------
__global__ __launch_bounds__(256) void gather_kernel(
    const unsigned long long* __restrict__ packed, float* __restrict__ out_idx,
    const short* __restrict__ zimgb, short* __restrict__ zselb) {
  const int w = threadIdx.x >> 6, l = threadIdx.x & 63;
  const int n = blockIdx.x * 4 + w;
  const unsigned long long p = packed[n];
  int4 v = {0, 0, 0, 0};
  float f = -1.0f;
  if (p != 0xFFFFFFFFFFFFFFFFull) {
    const int sel = (int)(p & 0xFFFFFFFFull);
    f = (float)sel;
    v = ((const int4*)(zimgb + (size_t)sel * DIM))[l];
  }
  ((int4*)(zselb + (size_t)n * DIM))[l] = v;
  if (l == 0) out_idx[n] = f;
}

// ---------------- merged bf16 MFMA GEMM (round-0 verbatim) ---------------------
// REVERT: rounds 1-4's 256x256/512-thread/1-block-per-CU variants all pinned at
// ~2.2 staged-B/cyc/CU (420-452 us) across four mechanistically distinct
// schedules (nt vs plain stores, ring depth, counted vmcnt, BK=32/64, bank
// conflicts 7.8M->0, L2 working-set remap). This 128x128/256-thread/2-block-CU
// structure measured ~250 us in round 0. Do not touch; gather its counters.
// blockIdx.y < 128 : C_ap[bm..][bn..] = zimg * ztxt^T * t + b          (no loss)
// blockIdx.y >= 128: C_fl[...]        = zsel * ztxt^T * t + b, fused loss
// 128x128 tile, BK=32, 4 waves 2x2, 4x4 mfma_f32_16x16x32_bf16 per wave.
__global__ __launch_bounds__(256) void gemm_merged(
    const short* __restrict__ Aimg, const short* __restrict__ Asel,
    const short* __restrict__ B, float* __restrict__ Cap,
    float* __restrict__ Cfl, const float* __restrict__ logt_p,
    const float* __restrict__ bias_p, float* __restrict__ loss_out) {
  __shared__ alignas(16) short As[128 * 32];
  __shared__ alignas(16) short Bs[128 * 32];
  __shared__ float red[4];

  const int t = threadIdx.x;
  const int w = t >> 6, l = t & 63;
  const int wm = w >> 1, wn = w & 1;
  const int bn = blockIdx.x * 128;               // x = col-block (fastest: B reuse)
  const bool fuse = (blockIdx.y >= 128);
  const int bm = (fuse ? (blockIdx.y - 128) : blockIdx.y) * 128;
  const short* A = fuse ? Asel : Aimg;
  float* C = fuse ? Cfl : Cap;
  const int fr = l & 15, quad = l >> 4;

  const int srow_base = (w << 4) + (l >> 2);     // staging row within 64-row group
  const int sq = l & 3;                          // staging 16B chunk

  f32x4 acc[4][4] = {};

  for (int k0 = 0; k0 < KDIM; k0 += 32) {
    __syncthreads();  // prior iter's ds_reads done before LDS overwrite
#pragma unroll
    for (int c = 0; c < 2; ++c) {
      const int row = c * 64 + srow_base;
      const int qg = sq ^ ((row >> 1) & 3);
      const short* gpa = A + (size_t)(bm + row) * KDIM + k0 + qg * 8;
      const short* lpa = &As[(c * 64 + (w << 4)) * 32];  // wave-uniform base
      __builtin_amdgcn_global_load_lds(
          (const __attribute__((address_space(1))) void*)gpa,
          (__attribute__((address_space(3))) void*)lpa, 16, 0, 0);
      const short* gpb = B + (size_t)(bn + row) * KDIM + k0 + qg * 8;
      const short* lpb = &Bs[(c * 64 + (w << 4)) * 32];
      __builtin_amdgcn_global_load_lds(
          (const __attribute__((address_space(1))) void*)gpb,
          (__attribute__((address_space(3))) void*)lpb, 16, 0, 0);
    }
    __syncthreads();  // drains vmcnt(0): staged data visible

    bf16x8 af[4], bfr[4];
#pragma unroll
    for (int mi = 0; mi < 4; ++mi) {
      const int ar = wm * 64 + mi * 16 + fr;
      af[mi] = *(const bf16x8*)&As[ar * 32 + (quad ^ ((ar >> 1) & 3)) * 8];
      const int br = wn * 64 + mi * 16 + fr;
      bfr[mi] = *(const bf16x8*)&Bs[br * 32 + (quad ^ ((br >> 1) & 3)) * 8];
    }
#pragma unroll
    for (int mi = 0; mi < 4; ++mi)
#pragma unroll
      for (int nj = 0; nj < 4; ++nj)
        acc[mi][nj] = __builtin_amdgcn_mfma_f32_16x16x32_bf16(
            af[mi], bfr[nj], acc[mi][nj], 0, 0, 0);
  }

  const float tt = expf(logt_p[0]);
  const float bb = bias_p[0];
  float lsum = 0.0f;
#pragma unroll
  for (int mi = 0; mi < 4; ++mi) {
#pragma unroll
    for (int nj = 0; nj < 4; ++nj) {
      const int grow0 = bm + wm * 64 + mi * 16 + quad * 4;
      const int gcol  = bn + wn * 64 + nj * 16 + fr;
      f32x4 a = acc[mi][nj];
#pragma unroll
      for (int r = 0; r < 4; ++r) {
        const float v = a[r] * tt + bb;
        C[(size_t)(grow0 + r) * N_TXT + gcol] = v;
        if (fuse) {
          const float lab = (grow0 + r == gcol) ? 1.0f : -1.0f;
          lsum += softplus_f(-lab * v);
        }
      }
    }
  }
  if (fuse) {
#pragma unroll
    for (int off = 32; off; off >>= 1) lsum += __shfl_xor(lsum, off, 64);
    if (l == 0) red[w] = lsum;
    __syncthreads();
    if (t == 0)
      atomicAdd(loss_out, (red[0] + red[1] + red[2] + red[3]) * (1.0f / N_TXT));
  }
}

// ---------------- launch --------------------------------------------------------
extern "C" void kernel_launch(void* const* d_in, const int* in_sizes, int n_in,
                              void* d_out, int out_size, void* d_ws, size_t ws_size,
                              hipStream_t stream) {
  const float* img  = (const float*)d_in[0];
  const float* txt  = (const float*)d_in[1];
  const int*   key  = (const int*)d_in[2];
  const float* logt = (const float*)d_in[3];
  const float* bias = (const float*)d_in[4];

  float* out    = (float*)d_out;
  float* o_loss = out;                                   // [1]
  float* o_sel  = out + 1;                               // [N]
  float* o_zimg = o_sel + N_TXT;                         // [S, 512]
  float* o_ztxt = o_zimg + (size_t)S_IMG * DIM;          // [N, 512]
  float* o_ap   = o_ztxt + (size_t)N_TXT * DIM;          // [S, N]
  float* o_fl   = o_ap + (size_t)S_IMG * N_TXT;          // [N, N]

  char* ws = (char*)d_ws;
  short* zimgb = (short*)ws;                                         // 16 MB
  short* ztxtb = (short*)(ws + (size_t)S_IMG * DIM * 2);             //  4 MB
  short* zselb = (short*)(ws + (size_t)(S_IMG + N_TXT) * DIM * 2);   //  4 MB
  unsigned long long* packed =
      (unsigned long long*)(ws + (size_t)(S_IMG + 2 * N_TXT) * DIM * 2);

  init_kernel<<<N_TXT / 256, 256, 0, stream>>>(packed, o_loss);
  normalize_kernel<<<N_TXT / 4, 256, 0, stream>>>(txt, o_ztxt, ztxtb);
  normalize_img_tp_kernel<<<S_IMG / 4, 256, 0, stream>>>(
      img, o_zimg, zimgb, o_ztxt, key, packed, logt, bias);
  gather_kernel<<<N_TXT / 4, 256, 0, stream>>>(packed, o_sel, zimgb, zselb);
  gemm_merged<<<dim3(N_TXT / 128, S_IMG / 128 + N_TXT / 128), 256, 0, stream>>>(
      zimgb, zselb, ztxtb, o_ap, o_fl, logt, bias, o_loss);
}